// Round 1
// baseline (7466.276 us; speedup 1.0000x reference)
//
#include <hip/hip_runtime.h>
#include <hip/hip_bf16.h>
#include <math.h>

#define BATCH 256
#define CCH 768
#define LCH 64
#define PP 81

// ---------------- KW: weight composition ----------------
// WA[o][c] = sum_{k<512} W11[o][k]*Wh2[k][c]
// WB[o][l] = sum_{k<256} W11[o][512+k]*Wl1[k][l]
// beff[o]  = W11[o,:512]·bh2 + W11[o,512:]·bl1 + b11[o]
__global__ __launch_bounds__(256) void kw_compose(
    const float* __restrict__ W11, const float* __restrict__ Wh2,
    const float* __restrict__ Wl1, const float* __restrict__ bh2,
    const float* __restrict__ bl1, const float* __restrict__ b11,
    float* __restrict__ WA, float* __restrict__ WB, float* __restrict__ beff)
{
    int o = blockIdx.x;
    int t = threadIdx.x;
    const float* w11row = W11 + (size_t)o * CCH;
    for (int c = t; c < CCH; c += 256) {
        float s = 0.f;
        for (int k = 0; k < 512; ++k) s = fmaf(w11row[k], Wh2[(size_t)k*CCH + c], s);
        WA[(size_t)o*CCH + c] = s;
    }
    if (t < LCH) {
        float s = 0.f;
        for (int k = 0; k < 256; ++k) s = fmaf(w11row[512+k], Wl1[k*LCH + t], s);
        WB[o*LCH + t] = s;
    }
    if (t == 0) {
        float s = b11[o];
        for (int k = 0; k < 512; ++k) s = fmaf(w11row[k], bh2[k], s);
        for (int k = 0; k < 256; ++k) s = fmaf(w11row[512+k], bl1[k], s);
        beff[o] = s;
    }
}

// ---------------- K1: fuse_1 / fuse_2 (per-position 1x1 convs as GEMM) ------
// fuse_1[b,o,p] = Wh1[o,:]·x[b,:,p] + bh1[o]
// fuse_2[b,o,p] = WA[o,:]·x[b,:,p] + WB[o,:]·y[b,:,p] + beff[o]
__global__ __launch_bounds__(256) void k_fuse12(
    const float* __restrict__ x, const float* __restrict__ y,
    const float* __restrict__ Wh1, const float* __restrict__ bh1,
    const float* __restrict__ WA, const float* __restrict__ WB,
    const float* __restrict__ beff,
    float* __restrict__ f1, float* __restrict__ f2)
{
    int b  = blockIdx.x;
    int o0 = blockIdx.y * 64;
    int tid = threadIdx.x;
    int pl = tid & 15;       // position lane
    int ol = tid >> 4;       // output lane (16), each owns 4 o's
    __shared__ float xs[64*96];     // c-chunk x positions (pad 81->96, zeros)
    __shared__ float w1s[64*65];    // +1 pad breaks o-stride bank conflicts
    __shared__ float wAs[64*65];
    float acc1[4][6] = {};
    float acc2[4][6] = {};
    const float* xb = x + (size_t)b * CCH * PP;
    for (int c0 = 0; c0 < CCH; c0 += 64) {
        __syncthreads();
        for (int i = tid; i < 64*96; i += 256) {
            int cc = i / 96, p = i - cc*96;
            xs[i] = (p < PP) ? xb[(size_t)(c0+cc)*PP + p] : 0.f;
        }
        for (int i = tid; i < 64*64; i += 256) {
            int oo = i >> 6, cc = i & 63;
            w1s[oo*65+cc] = Wh1[(size_t)(o0+oo)*CCH + c0 + cc];
            wAs[oo*65+cc] = WA [(size_t)(o0+oo)*CCH + c0 + cc];
        }
        __syncthreads();
        for (int c = 0; c < 64; ++c) {
            float xv[6];
            #pragma unroll
            for (int s = 0; s < 6; ++s) xv[s] = xs[c*96 + pl + 16*s];
            #pragma unroll
            for (int j = 0; j < 4; ++j) {
                float a1 = w1s[(ol+16*j)*65 + c];
                float a2 = wAs[(ol+16*j)*65 + c];
                #pragma unroll
                for (int s = 0; s < 6; ++s) {
                    acc1[j][s] = fmaf(a1, xv[s], acc1[j][s]);
                    acc2[j][s] = fmaf(a2, xv[s], acc2[j][s]);
                }
            }
        }
    }
    // y extension (fuse_2 only), K = 64
    __syncthreads();
    const float* yb = y + (size_t)b * LCH * PP;
    for (int i = tid; i < 64*96; i += 256) {
        int cc = i / 96, p = i - cc*96;
        xs[i] = (p < PP) ? yb[(size_t)cc*PP + p] : 0.f;
    }
    for (int i = tid; i < 64*64; i += 256) {
        int oo = i >> 6, ll = i & 63;
        wAs[oo*65+ll] = WB[(o0+oo)*LCH + ll];
    }
    __syncthreads();
    for (int l = 0; l < 64; ++l) {
        float yv[6];
        #pragma unroll
        for (int s = 0; s < 6; ++s) yv[s] = xs[l*96 + pl + 16*s];
        #pragma unroll
        for (int j = 0; j < 4; ++j) {
            float a2 = wAs[(ol+16*j)*65 + l];
            #pragma unroll
            for (int s = 0; s < 6; ++s) acc2[j][s] = fmaf(a2, yv[s], acc2[j][s]);
        }
    }
    #pragma unroll
    for (int j = 0; j < 4; ++j) {
        int o = o0 + ol + 16*j;
        float bb1 = bh1[o], bb2 = beff[o];
        #pragma unroll
        for (int s = 0; s < 6; ++s) {
            int p = pl + 16*s;
            if (p < PP) {
                size_t idx = ((size_t)b*CCH + o)*PP + p;
                f1[idx] = acc1[j][s] + bb1;
                f2[idx] = acc2[j][s] + bb2;
            }
        }
    }
}

// ---------------- S1: fuse_3 / fuse_4 (tiny, folded through w_conv1_2) ------
__global__ __launch_bounds__(256) void k_fuse34(
    const float* __restrict__ x, const float* __restrict__ y,
    const float* __restrict__ wh3, const float* __restrict__ bh3,
    const float* __restrict__ wl2, const float* __restrict__ bl2,
    const float* __restrict__ W12, const float* __restrict__ b12,
    const float* __restrict__ Wl3, const float* __restrict__ bl3,
    float* __restrict__ f3, float* __restrict__ f4)
{
    int t = blockIdx.x * 256 + threadIdx.x;
    if (t >= BATCH*PP) return;
    int b = t / PP, p = t - b*PP;
    const float* xb = x + (size_t)b*CCH*PP + p;
    const float* yb = y + (size_t)b*LCH*PP + p;
    float sx = 0.f;
    for (int c = 0; c < CCH; ++c) sx = fmaf(wh3[c], xb[(size_t)c*PP], sx);
    float sy = 0.f, s40 = 0.f, s41 = 0.f;
    for (int l = 0; l < LCH; ++l) {
        float v = yb[(size_t)l*PP];
        sy  = fmaf(wl2[l], v, sy);
        s40 = fmaf(Wl3[l], v, s40);
        s41 = fmaf(Wl3[LCH+l], v, s41);
    }
    float t3a = sx + bh3[0];
    float t3b = sy + bl2[0];
    f3[(b*2+0)*PP+p] = W12[0]*t3a + W12[1]*t3b + b12[0];
    f3[(b*2+1)*PP+p] = W12[2]*t3a + W12[3]*t3b + b12[1];
    f4[(b*2+0)*PP+p] = s40 + bl3[0];
    f4[(b*2+1)*PP+p] = s41 + bl3[1];
}

// ---------------- S2: 5 SSIM fields, box-7 filter along w then h ------------
// A layout: [b][f=k*5+{x,y,xx,yy,xy}][81]
__global__ __launch_bounds__(128) void k_ssim_wh(
    const float* __restrict__ f3, const float* __restrict__ f4,
    float* __restrict__ A)
{
    int b = blockIdx.x;
    int tid = threadIdx.x;
    __shared__ float z[10][81];
    __shared__ float tb[10][81];
    for (int i = tid; i < 2*81; i += 128) {
        int k = i / 81, p = i - k*81;
        float a = f3[(b*2+k)*81+p];
        float c = f4[(b*2+k)*81+p];
        z[k*5+0][p] = a;   z[k*5+1][p] = c;
        z[k*5+2][p] = a*a; z[k*5+3][p] = c*c; z[k*5+4][p] = a*c;
    }
    __syncthreads();
    for (int i = tid; i < 10*81; i += 128) {
        int f = i / 81, p = i - f*81;
        int yy = p/9, xx = p - yy*9;
        float s = 0.f;
        #pragma unroll
        for (int d = -3; d <= 3; ++d) {
            int j = xx + d;
            j = (j < 0) ? (-1-j) : ((j > 8) ? (17-j) : j);  // symmetric reflect
            s += z[f][yy*9+j];
        }
        tb[f][p] = s * (1.f/7.f);
    }
    __syncthreads();
    for (int i = tid; i < 10*81; i += 128) {
        int f = i / 81, p = i - f*81;
        int yy = p/9, xx = p - yy*9;
        float s = 0.f;
        #pragma unroll
        for (int d = -3; d <= 3; ++d) {
            int j = yy + d;
            j = (j < 0) ? (-1-j) : ((j > 8) ? (17-j) : j);
            s += tb[f][j*9+xx];
        }
        A[((size_t)b*10 + f)*81 + p] = s * (1.f/7.f);
    }
}

// ---------------- S3: box-7 filter along batch axis (cross-batch!) ----------
__global__ __launch_bounds__(256) void k_ssim_b(
    const float* __restrict__ A, float* __restrict__ U)
{
    int col = blockIdx.x;          // 0..809 = f*81+p
    int b = threadIdx.x;           // 0..255
    float s = 0.f;
    #pragma unroll
    for (int d = -3; d <= 3; ++d) {
        int j = b + d;
        j = (j < 0) ? (-1-j) : ((j > 255) ? (511-j) : j);
        s += A[(size_t)j*810 + col];
    }
    U[(size_t)b*810 + col] = s * (1.f/7.f);
}

// ---------------- S4: SSIM map + fuse2_2 + cc(ssim) -------------------------
__global__ __launch_bounds__(256) void k_ssim_comb(
    const float* __restrict__ U, const float* __restrict__ f3,
    const float* __restrict__ f4, const float* __restrict__ wcc,
    const float* __restrict__ bcc,
    float* __restrict__ f22, float* __restrict__ ccs)
{
    int t = blockIdx.x * 256 + threadIdx.x;
    if (t >= BATCH*81) return;
    int b = t / 81, p = t - b*81;
    const float cov = 343.f/342.f, C1c = 1e-4f, C2c = 9e-4f;
    float S[2];
    #pragma unroll
    for (int k = 0; k < 2; ++k) {
        const float* u = U + (size_t)b*810 + (k*5)*81 + p;
        float ux = u[0], uy = u[81], uxx = u[162], uyy = u[243], uxy = u[324];
        float vx = cov*(uxx - ux*ux), vy = cov*(uyy - uy*uy), vxy = cov*(uxy - ux*uy);
        S[k] = ((2.f*ux*uy + C1c)*(2.f*vxy + C2c)) /
               ((ux*ux + uy*uy + C1c)*(vx + vy + C2c));
    }
    float a0 = f4[(b*2+0)*81+p] + S[0]*f3[(b*2+0)*81+p];
    float a1 = f4[(b*2+1)*81+p] + S[1]*f3[(b*2+1)*81+p];
    f22[t] = wcc[0]*a0 + wcc[1]*a1 + bcc[0];
    ccs[t] = wcc[0]*S[0] + wcc[1]*S[1] + bcc[0];
}

// ---------------- C1: channel sums -> alpha, gamma (cor_1 / cor2_1 folded) --
__global__ __launch_bounds__(256) void k_cor(
    const float* __restrict__ f1, const float* __restrict__ f2,
    const float* __restrict__ f22, const float* __restrict__ ccs,
    float* __restrict__ alpha, float* __restrict__ gamma)
{
    int t = blockIdx.x * 256 + threadIdx.x;
    if (t >= BATCH*81) return;
    int b = t / 81, p = t - b*81;
    const float* a = f1 + (size_t)b*CCH*PP + p;
    const float* c = f2 + (size_t)b*CCH*PP + p;
    float Sxx=0.f, Syy=0.f, Sxy=0.f, Sx=0.f, Sy=0.f;
    for (int i = 0; i < CCH; ++i) {
        float u = a[(size_t)i*PP], v = c[(size_t)i*PP];
        Sxx = fmaf(u,u,Sxx); Syy = fmaf(v,v,Syy); Sxy = fmaf(u,v,Sxy);
        Sx += u; Sy += v;
    }
    float cor1 = Sxy / fmaxf(sqrtf(Sxx)*sqrtf(Syy), 1e-8f);
    float al = 0.5f*(1.f - cor1);
    // fuse2_1 = f1 + al*f2 ; its sum & norm from the same 5 sums
    float sum21 = Sx + al*Sy;
    float n21 = sqrtf(fmaxf(Sxx + 2.f*al*Sxy + al*al*Syy, 0.f));
    float fv = f22[t];
    // cossim(fuse2_1, broadcast(f22)): num = fv*sum21, den = n21*sqrt(768)*|fv|
    float cor2 = (fv * sum21) / fmaxf(n21 * 27.712812921102035f * fabsf(fv), 1e-8f);
    float be = 0.5f*(1.f - cor2 + ccs[t]);
    alpha[t] = al;
    gamma[t] = be * fv;
}

// ---------------- F: pool conv + xc + fc1(gelu) + fc2(leaky) -> xweight -----
__global__ __launch_bounds__(128) void k_fc(
    const float* __restrict__ f22,
    const float* __restrict__ wpool, const float* __restrict__ bpool,
    const float* __restrict__ Wfc1, const float* __restrict__ bfc1,
    const float* __restrict__ Wfc2, const float* __restrict__ bfc2,
    float* __restrict__ xw)
{
    int b = blockIdx.x;
    int tid = threadIdx.x;
    __shared__ float xc[324];
    __shared__ float h1[324];
    for (int p = tid; p < 81; p += 128) {
        float v = f22[b*81+p];
        xc[p] = v; xc[243+p] = v;
    }
    __syncthreads();
    for (int i = tid; i < 162; i += 128) {
        int k = i / 81, p = i - k*81;
        int yy = p/9, xx = p - yy*9;
        float s = bpool[k];
        #pragma unroll
        for (int dy = -1; dy <= 1; ++dy)
            #pragma unroll
            for (int dx = -1; dx <= 1; ++dx) {
                int Y = yy+dy, X = xx+dx;
                if (Y >= 0 && Y < 9 && X >= 0 && X < 9)
                    s = fmaf(wpool[k*9 + (dy+1)*3 + (dx+1)], xc[Y*9+X], s);
            }
        xc[81+i] = s;
    }
    __syncthreads();
    for (int i = tid; i < 324; i += 128) {
        float s = bfc1[i];
        const float* wr = Wfc1 + (size_t)i*324;
        for (int j = 0; j < 324; ++j) s = fmaf(wr[j], xc[j], s);
        h1[i] = 0.5f*s*(1.f + erff(s*0.70710678118654752f));  // exact gelu
    }
    __syncthreads();
    for (int q = tid; q < 81; q += 128) {
        float s = bfc2[q];
        const float* wr = Wfc2 + (size_t)q*324;
        for (int j = 0; j < 324; ++j) s = fmaf(wr[j], h1[j], s);
        xw[b*81+q] = (s > 0.f) ? s : 0.01f*s;
    }
}

// ---------------- KB: 3x3 bconv + BN + leaky, input built on the fly --------
// in[b,c,p] = (1+xw[b,p]) * (f1[b,c,p] + alpha[b,p]*f2[b,c,p] + gamma[b,p])
__global__ __launch_bounds__(256) void k_bconv(
    const float* __restrict__ f1, const float* __restrict__ f2,
    const float* __restrict__ alpha, const float* __restrict__ gamma,
    const float* __restrict__ xw,
    const float* __restrict__ Wb,
    const float* __restrict__ bn_g, const float* __restrict__ bn_b,
    const float* __restrict__ bn_m, const float* __restrict__ bn_v,
    float* __restrict__ out)
{
    int b0 = blockIdx.x * 2;
    int o0 = blockIdx.y * 64;
    int tid = threadIdx.x;
    int pl = tid & 31;       // position lane
    int ol = tid >> 5;       // 8 output lanes, each owns 8 o's
    __shared__ float ins[2*16*82];   // [bi][c][82]; slot 81 is the zero slot
    __shared__ float wt[64*16*12];   // [o][c][12]; taps padded 9->12 for float4
    __shared__ float scm[2*81], sal[2*81], sga[2*81];

    for (int i = tid; i < 2*81; i += 256) {
        int bi = i / 81, p = i - bi*81;
        int bb = b0 + bi;
        scm[i] = 1.f + xw[bb*81+p];
        sal[i] = alpha[bb*81+p];
        sga[i] = gamma[bb*81+p];
    }

    int iidx[3][9];
    #pragma unroll
    for (int s = 0; s < 3; ++s) {
        int p = pl + 32*s;
        int yy = p / 9, xx = p - yy*9;
        #pragma unroll
        for (int t = 0; t < 9; ++t) {
            int Y = yy + t/3 - 1, X = xx + (t%3) - 1;
            bool ok = (p < 81) && Y >= 0 && Y < 9 && X >= 0 && X < 9;
            iidx[s][t] = ok ? (Y*9 + X) : 81;   // 81 -> staged zero
        }
    }

    float acc[2][8][3] = {};

    for (int c0 = 0; c0 < CCH; c0 += 16) {
        __syncthreads();
        for (int i = tid; i < 2*16*82; i += 256) {
            int bi = i / (16*82);
            int r  = i - bi*16*82;
            int c  = r / 82, p = r - c*82;
            float v = 0.f;
            if (p < 81) {
                size_t gidx = ((size_t)(b0+bi)*CCH + c0 + c)*PP + p;
                int sp = bi*81 + p;
                v = scm[sp] * (f1[gidx] + sal[sp]*f2[gidx] + sga[sp]);
            }
            ins[i] = v;
        }
        for (int i = tid; i < 64*16*12; i += 256) {
            int o = i / 192;
            int r = i - o*192;
            int c = r / 12, t = r - c*12;
            wt[i] = (t < 9) ? Wb[((size_t)(o0+o)*CCH + c0 + c)*9 + t] : 0.f;
        }
        __syncthreads();
        for (int c = 0; c < 16; ++c) {
            float4 w4[8][3];
            #pragma unroll
            for (int j = 0; j < 8; ++j) {
                const float4* wp = (const float4*)&wt[((ol + 8*j)*16 + c)*12];
                w4[j][0] = wp[0]; w4[j][1] = wp[1]; w4[j][2] = wp[2];
            }
            #pragma unroll
            for (int bi = 0; bi < 2; ++bi) {
                float iv[3][9];
                #pragma unroll
                for (int s = 0; s < 3; ++s)
                    #pragma unroll
                    for (int t = 0; t < 9; ++t)
                        iv[s][t] = ins[bi*(16*82) + c*82 + iidx[s][t]];
                #pragma unroll
                for (int j = 0; j < 8; ++j)
                    #pragma unroll
                    for (int s = 0; s < 3; ++s) {
                        float a = acc[bi][j][s];
                        a = fmaf(w4[j][0].x, iv[s][0], a);
                        a = fmaf(w4[j][0].y, iv[s][1], a);
                        a = fmaf(w4[j][0].z, iv[s][2], a);
                        a = fmaf(w4[j][0].w, iv[s][3], a);
                        a = fmaf(w4[j][1].x, iv[s][4], a);
                        a = fmaf(w4[j][1].y, iv[s][5], a);
                        a = fmaf(w4[j][1].z, iv[s][6], a);
                        a = fmaf(w4[j][1].w, iv[s][7], a);
                        a = fmaf(w4[j][2].x, iv[s][8], a);
                        acc[bi][j][s] = a;
                    }
            }
        }
    }
    #pragma unroll
    for (int j = 0; j < 8; ++j) {
        int o = o0 + ol + 8*j;
        float sc = bn_g[o] * rsqrtf(bn_v[o] + 1e-5f);
        float mn = bn_m[o], bt = bn_b[o];
        #pragma unroll
        for (int bi = 0; bi < 2; ++bi)
            #pragma unroll
            for (int s = 0; s < 3; ++s) {
                int p = pl + 32*s;
                if (p < 81) {
                    float v = (acc[bi][j][s] - mn) * sc + bt;
                    out[((size_t)(b0+bi)*CCH + o)*PP + p] = (v > 0.f) ? v : 0.01f*v;
                }
            }
    }
}

extern "C" void kernel_launch(void* const* d_in, const int* in_sizes, int n_in,
                              void* d_out, int out_size, void* d_ws, size_t ws_size,
                              hipStream_t stream)
{
    (void)in_sizes; (void)n_in; (void)out_size; (void)ws_size;
    const float* x    = (const float*)d_in[0];
    const float* y    = (const float*)d_in[1];
    const float* Wh1  = (const float*)d_in[2];
    const float* bh1  = (const float*)d_in[3];
    const float* W11  = (const float*)d_in[4];
    const float* b11  = (const float*)d_in[5];
    const float* Wh2  = (const float*)d_in[6];
    const float* bh2  = (const float*)d_in[7];
    const float* Wl1  = (const float*)d_in[8];
    const float* bl1  = (const float*)d_in[9];
    const float* wh3  = (const float*)d_in[10];
    const float* bh3  = (const float*)d_in[11];
    const float* wl2  = (const float*)d_in[12];
    const float* bl2  = (const float*)d_in[13];
    const float* W12  = (const float*)d_in[14];
    const float* b12  = (const float*)d_in[15];
    const float* Wl3  = (const float*)d_in[16];
    const float* bl3  = (const float*)d_in[17];
    const float* wcc  = (const float*)d_in[18];
    const float* bcc  = (const float*)d_in[19];
    const float* wpool= (const float*)d_in[20];
    const float* bpool= (const float*)d_in[21];
    const float* Wfc1 = (const float*)d_in[22];
    const float* bfc1 = (const float*)d_in[23];
    const float* Wfc2 = (const float*)d_in[24];
    const float* bfc2 = (const float*)d_in[25];
    const float* Wb   = (const float*)d_in[26];
    const float* bng  = (const float*)d_in[27];
    const float* bnb  = (const float*)d_in[28];
    const float* bnm  = (const float*)d_in[29];
    const float* bnv  = (const float*)d_in[30];
    float* out = (float*)d_out;
    float* ws = (float*)d_ws;

    size_t off = 0;
    float* f1    = ws + off; off += (size_t)BATCH*CCH*PP;   // 15.93M
    float* f2    = ws + off; off += (size_t)BATCH*CCH*PP;   // 15.93M
    float* WA    = ws + off; off += (size_t)CCH*CCH;
    float* WB    = ws + off; off += (size_t)CCH*LCH;
    float* beff  = ws + off; off += CCH;
    float* f3    = ws + off; off += BATCH*2*PP;
    float* f4    = ws + off; off += BATCH*2*PP;
    float* Af    = ws + off; off += BATCH*10*PP;
    float* Uf    = ws + off; off += BATCH*10*PP;
    float* f22   = ws + off; off += BATCH*PP;
    float* ccs   = ws + off; off += BATCH*PP;
    float* alpha = ws + off; off += BATCH*PP;
    float* gamma = ws + off; off += BATCH*PP;
    float* xw    = ws + off; off += BATCH*PP;
    // total ~132.4 MB of d_ws

    kw_compose<<<dim3(CCH), dim3(256), 0, stream>>>(W11, Wh2, Wl1, bh2, bl1, b11, WA, WB, beff);
    k_fuse12<<<dim3(BATCH,12), dim3(256), 0, stream>>>(x, y, Wh1, bh1, WA, WB, beff, f1, f2);
    k_fuse34<<<dim3(81), dim3(256), 0, stream>>>(x, y, wh3, bh3, wl2, bl2, W12, b12, Wl3, bl3, f3, f4);
    k_ssim_wh<<<dim3(BATCH), dim3(128), 0, stream>>>(f3, f4, Af);
    k_ssim_b<<<dim3(810), dim3(256), 0, stream>>>(Af, Uf);
    k_ssim_comb<<<dim3(81), dim3(256), 0, stream>>>(Uf, f3, f4, wcc, bcc, f22, ccs);
    k_fc<<<dim3(BATCH), dim3(128), 0, stream>>>(f22, wpool, bpool, Wfc1, bfc1, Wfc2, bfc2, xw);
    k_cor<<<dim3(81), dim3(256), 0, stream>>>(f1, f2, f22, ccs, alpha, gamma);
    k_bconv<<<dim3(BATCH/2,12), dim3(256), 0, stream>>>(f1, f2, alpha, gamma, xw, Wb, bng, bnb, bnm, bnv, out);
}

// Round 2
// 1905.345 us; speedup vs baseline: 3.9186x; 3.9186x over previous
//
#include <hip/hip_runtime.h>
#include <hip/hip_bf16.h>
#include <math.h>

#define BATCH 256
#define CCH 768
#define LCH 64
#define PP 81

typedef __attribute__((ext_vector_type(8))) short short8v;
typedef __attribute__((ext_vector_type(4))) float f32x4;

// ---------------- KW: weight composition ----------------
__global__ __launch_bounds__(256) void kw_compose(
    const float* __restrict__ W11, const float* __restrict__ Wh2,
    const float* __restrict__ Wl1, const float* __restrict__ bh2,
    const float* __restrict__ bl1, const float* __restrict__ b11,
    float* __restrict__ WA, float* __restrict__ WB, float* __restrict__ beff)
{
    int o = blockIdx.x;
    int t = threadIdx.x;
    const float* w11row = W11 + (size_t)o * CCH;
    for (int c = t; c < CCH; c += 256) {
        float s = 0.f;
        for (int k = 0; k < 512; ++k) s = fmaf(w11row[k], Wh2[(size_t)k*CCH + c], s);
        WA[(size_t)o*CCH + c] = s;
    }
    if (t < LCH) {
        float s = 0.f;
        for (int k = 0; k < 256; ++k) s = fmaf(w11row[512+k], Wl1[k*LCH + t], s);
        WB[o*LCH + t] = s;
    }
    if (t == 0) {
        float s = b11[o];
        for (int k = 0; k < 512; ++k) s = fmaf(w11row[k], bh2[k], s);
        for (int k = 0; k < 256; ++k) s = fmaf(w11row[512+k], bl1[k], s);
        beff[o] = s;
    }
}

// ---------------- K1: fuse_1 / fuse_2 (unchanged fp32 path) ------
__global__ __launch_bounds__(256) void k_fuse12(
    const float* __restrict__ x, const float* __restrict__ y,
    const float* __restrict__ Wh1, const float* __restrict__ bh1,
    const float* __restrict__ WA, const float* __restrict__ WB,
    const float* __restrict__ beff,
    float* __restrict__ f1, float* __restrict__ f2)
{
    int b  = blockIdx.x;
    int o0 = blockIdx.y * 64;
    int tid = threadIdx.x;
    int pl = tid & 15;
    int ol = tid >> 4;
    __shared__ float xs[64*96];
    __shared__ float w1s[64*65];
    __shared__ float wAs[64*65];
    float acc1[4][6] = {};
    float acc2[4][6] = {};
    const float* xb = x + (size_t)b * CCH * PP;
    for (int c0 = 0; c0 < CCH; c0 += 64) {
        __syncthreads();
        for (int i = tid; i < 64*96; i += 256) {
            int cc = i / 96, p = i - cc*96;
            xs[i] = (p < PP) ? xb[(size_t)(c0+cc)*PP + p] : 0.f;
        }
        for (int i = tid; i < 64*64; i += 256) {
            int oo = i >> 6, cc = i & 63;
            w1s[oo*65+cc] = Wh1[(size_t)(o0+oo)*CCH + c0 + cc];
            wAs[oo*65+cc] = WA [(size_t)(o0+oo)*CCH + c0 + cc];
        }
        __syncthreads();
        for (int c = 0; c < 64; ++c) {
            float xv[6];
            #pragma unroll
            for (int s = 0; s < 6; ++s) xv[s] = xs[c*96 + pl + 16*s];
            #pragma unroll
            for (int j = 0; j < 4; ++j) {
                float a1 = w1s[(ol+16*j)*65 + c];
                float a2 = wAs[(ol+16*j)*65 + c];
                #pragma unroll
                for (int s = 0; s < 6; ++s) {
                    acc1[j][s] = fmaf(a1, xv[s], acc1[j][s]);
                    acc2[j][s] = fmaf(a2, xv[s], acc2[j][s]);
                }
            }
        }
    }
    __syncthreads();
    const float* yb = y + (size_t)b * LCH * PP;
    for (int i = tid; i < 64*96; i += 256) {
        int cc = i / 96, p = i - cc*96;
        xs[i] = (p < PP) ? yb[(size_t)cc*PP + p] : 0.f;
    }
    for (int i = tid; i < 64*64; i += 256) {
        int oo = i >> 6, ll = i & 63;
        wAs[oo*65+ll] = WB[(o0+oo)*LCH + ll];
    }
    __syncthreads();
    for (int l = 0; l < 64; ++l) {
        float yv[6];
        #pragma unroll
        for (int s = 0; s < 6; ++s) yv[s] = xs[l*96 + pl + 16*s];
        #pragma unroll
        for (int j = 0; j < 4; ++j) {
            float a2 = wAs[(ol+16*j)*65 + l];
            #pragma unroll
            for (int s = 0; s < 6; ++s) acc2[j][s] = fmaf(a2, yv[s], acc2[j][s]);
        }
    }
    #pragma unroll
    for (int j = 0; j < 4; ++j) {
        int o = o0 + ol + 16*j;
        float bb1 = bh1[o], bb2 = beff[o];
        #pragma unroll
        for (int s = 0; s < 6; ++s) {
            int p = pl + 16*s;
            if (p < PP) {
                size_t idx = ((size_t)b*CCH + o)*PP + p;
                f1[idx] = acc1[j][s] + bb1;
                f2[idx] = acc2[j][s] + bb2;
            }
        }
    }
}

// ---------------- S1: fuse_3 / fuse_4 ------
__global__ __launch_bounds__(256) void k_fuse34(
    const float* __restrict__ x, const float* __restrict__ y,
    const float* __restrict__ wh3, const float* __restrict__ bh3,
    const float* __restrict__ wl2, const float* __restrict__ bl2,
    const float* __restrict__ W12, const float* __restrict__ b12,
    const float* __restrict__ Wl3, const float* __restrict__ bl3,
    float* __restrict__ f3, float* __restrict__ f4)
{
    int t = blockIdx.x * 256 + threadIdx.x;
    if (t >= BATCH*PP) return;
    int b = t / PP, p = t - b*PP;
    const float* xb = x + (size_t)b*CCH*PP + p;
    const float* yb = y + (size_t)b*LCH*PP + p;
    float sx = 0.f;
    for (int c = 0; c < CCH; ++c) sx = fmaf(wh3[c], xb[(size_t)c*PP], sx);
    float sy = 0.f, s40 = 0.f, s41 = 0.f;
    for (int l = 0; l < LCH; ++l) {
        float v = yb[(size_t)l*PP];
        sy  = fmaf(wl2[l], v, sy);
        s40 = fmaf(Wl3[l], v, s40);
        s41 = fmaf(Wl3[LCH+l], v, s41);
    }
    float t3a = sx + bh3[0];
    float t3b = sy + bl2[0];
    f3[(b*2+0)*PP+p] = W12[0]*t3a + W12[1]*t3b + b12[0];
    f3[(b*2+1)*PP+p] = W12[2]*t3a + W12[3]*t3b + b12[1];
    f4[(b*2+0)*PP+p] = s40 + bl3[0];
    f4[(b*2+1)*PP+p] = s41 + bl3[1];
}

// ---------------- S2: SSIM box-7 along w,h ------------
__global__ __launch_bounds__(128) void k_ssim_wh(
    const float* __restrict__ f3, const float* __restrict__ f4,
    float* __restrict__ A)
{
    int b = blockIdx.x;
    int tid = threadIdx.x;
    __shared__ float z[10][81];
    __shared__ float tb[10][81];
    for (int i = tid; i < 2*81; i += 128) {
        int k = i / 81, p = i - k*81;
        float a = f3[(b*2+k)*81+p];
        float c = f4[(b*2+k)*81+p];
        z[k*5+0][p] = a;   z[k*5+1][p] = c;
        z[k*5+2][p] = a*a; z[k*5+3][p] = c*c; z[k*5+4][p] = a*c;
    }
    __syncthreads();
    for (int i = tid; i < 10*81; i += 128) {
        int f = i / 81, p = i - f*81;
        int yy = p/9, xx = p - yy*9;
        float s = 0.f;
        #pragma unroll
        for (int d = -3; d <= 3; ++d) {
            int j = xx + d;
            j = (j < 0) ? (-1-j) : ((j > 8) ? (17-j) : j);
            s += z[f][yy*9+j];
        }
        tb[f][p] = s * (1.f/7.f);
    }
    __syncthreads();
    for (int i = tid; i < 10*81; i += 128) {
        int f = i / 81, p = i - f*81;
        int yy = p/9, xx = p - yy*9;
        float s = 0.f;
        #pragma unroll
        for (int d = -3; d <= 3; ++d) {
            int j = yy + d;
            j = (j < 0) ? (-1-j) : ((j > 8) ? (17-j) : j);
            s += tb[f][j*9+xx];
        }
        A[((size_t)b*10 + f)*81 + p] = s * (1.f/7.f);
    }
}

// ---------------- S3: box-7 along batch ----------
__global__ __launch_bounds__(256) void k_ssim_b(
    const float* __restrict__ A, float* __restrict__ U)
{
    int col = blockIdx.x;
    int b = threadIdx.x;
    float s = 0.f;
    #pragma unroll
    for (int d = -3; d <= 3; ++d) {
        int j = b + d;
        j = (j < 0) ? (-1-j) : ((j > 255) ? (511-j) : j);
        s += A[(size_t)j*810 + col];
    }
    U[(size_t)b*810 + col] = s * (1.f/7.f);
}

// ---------------- S4: SSIM map + fuse2_2 + cc(ssim) -------------------------
__global__ __launch_bounds__(256) void k_ssim_comb(
    const float* __restrict__ U, const float* __restrict__ f3,
    const float* __restrict__ f4, const float* __restrict__ wcc,
    const float* __restrict__ bcc,
    float* __restrict__ f22, float* __restrict__ ccs)
{
    int t = blockIdx.x * 256 + threadIdx.x;
    if (t >= BATCH*81) return;
    int b = t / 81, p = t - b*81;
    const float cov = 343.f/342.f, C1c = 1e-4f, C2c = 9e-4f;
    float S[2];
    #pragma unroll
    for (int k = 0; k < 2; ++k) {
        const float* u = U + (size_t)b*810 + (k*5)*81 + p;
        float ux = u[0], uy = u[81], uxx = u[162], uyy = u[243], uxy = u[324];
        float vx = cov*(uxx - ux*ux), vy = cov*(uyy - uy*uy), vxy = cov*(uxy - ux*uy);
        S[k] = ((2.f*ux*uy + C1c)*(2.f*vxy + C2c)) /
               ((ux*ux + uy*uy + C1c)*(vx + vy + C2c));
    }
    float a0 = f4[(b*2+0)*81+p] + S[0]*f3[(b*2+0)*81+p];
    float a1 = f4[(b*2+1)*81+p] + S[1]*f3[(b*2+1)*81+p];
    f22[t] = wcc[0]*a0 + wcc[1]*a1 + bcc[0];
    ccs[t] = wcc[0]*S[0] + wcc[1]*S[1] + bcc[0];
}

// ---------------- C1 v2: coalesced channel sums -> alpha, gamma -------------
// thread tid = cl*81+p (cl in 0..2); addr c0*81+tid is contiguous across tid.
__global__ __launch_bounds__(256) void k_cor2(
    const float* __restrict__ f1, const float* __restrict__ f2,
    const float* __restrict__ f22, const float* __restrict__ ccs,
    float* __restrict__ alpha, float* __restrict__ gamma)
{
    int b = blockIdx.x;
    int tid = threadIdx.x;
    bool act = tid < 243;
    float Sxx=0.f, Syy=0.f, Sxy=0.f, Sx=0.f, Sy=0.f;
    const float* A = f1 + (size_t)b*CCH*PP;
    const float* C = f2 + (size_t)b*CCH*PP;
    if (act) {
        for (int c0 = 0; c0 < CCH; c0 += 3) {
            float u = A[(size_t)c0*PP + tid];
            float v = C[(size_t)c0*PP + tid];
            Sxx = fmaf(u,u,Sxx); Syy = fmaf(v,v,Syy); Sxy = fmaf(u,v,Sxy);
            Sx += u; Sy += v;
        }
    }
    __shared__ float red[243][5];
    if (act) {
        red[tid][0]=Sxx; red[tid][1]=Syy; red[tid][2]=Sxy; red[tid][3]=Sx; red[tid][4]=Sy;
    }
    __syncthreads();
    if (tid < 81) {
        float xx = red[tid][0]+red[tid+81][0]+red[tid+162][0];
        float yy = red[tid][1]+red[tid+81][1]+red[tid+162][1];
        float xy = red[tid][2]+red[tid+81][2]+red[tid+162][2];
        float sx = red[tid][3]+red[tid+81][3]+red[tid+162][3];
        float sy = red[tid][4]+red[tid+81][4]+red[tid+162][4];
        float cor1 = xy / fmaxf(sqrtf(xx)*sqrtf(yy), 1e-8f);
        float al = 0.5f*(1.f - cor1);
        float sum21 = sx + al*sy;
        float n21 = sqrtf(fmaxf(xx + 2.f*al*xy + al*al*yy, 0.f));
        int t = b*81 + tid;
        float fv = f22[t];
        float cor2 = (fv * sum21) / fmaxf(n21 * 27.712812921102035f * fabsf(fv), 1e-8f);
        float be = 0.5f*(1.f - cor2 + ccs[t]);
        alpha[t] = al;
        gamma[t] = be * fv;
    }
}

// ---------------- F: pool conv + fc1(gelu) + fc2(leaky) -> xweight -----
__global__ __launch_bounds__(128) void k_fc(
    const float* __restrict__ f22,
    const float* __restrict__ wpool, const float* __restrict__ bpool,
    const float* __restrict__ Wfc1, const float* __restrict__ bfc1,
    const float* __restrict__ Wfc2, const float* __restrict__ bfc2,
    float* __restrict__ xw)
{
    int b = blockIdx.x;
    int tid = threadIdx.x;
    __shared__ float xc[324];
    __shared__ float h1[324];
    for (int p = tid; p < 81; p += 128) {
        float v = f22[b*81+p];
        xc[p] = v; xc[243+p] = v;
    }
    __syncthreads();
    for (int i = tid; i < 162; i += 128) {
        int k = i / 81, p = i - k*81;
        int yy = p/9, xx = p - yy*9;
        float s = bpool[k];
        #pragma unroll
        for (int dy = -1; dy <= 1; ++dy)
            #pragma unroll
            for (int dx = -1; dx <= 1; ++dx) {
                int Y = yy+dy, X = xx+dx;
                if (Y >= 0 && Y < 9 && X >= 0 && X < 9)
                    s = fmaf(wpool[k*9 + (dy+1)*3 + (dx+1)], xc[Y*9+X], s);
            }
        xc[81+i] = s;
    }
    __syncthreads();
    for (int i = tid; i < 324; i += 128) {
        float s = bfc1[i];
        const float* wr = Wfc1 + (size_t)i*324;
        for (int j = 0; j < 324; ++j) s = fmaf(wr[j], xc[j], s);
        h1[i] = 0.5f*s*(1.f + erff(s*0.70710678118654752f));
    }
    __syncthreads();
    for (int q = tid; q < 81; q += 128) {
        float s = bfc2[q];
        const float* wr = Wfc2 + (size_t)q*324;
        for (int j = 0; j < 324; ++j) s = fmaf(wr[j], h1[j], s);
        xw[b*81+q] = (s > 0.f) ? s : 0.01f*s;
    }
}

// ---------------- WP: Wb[o][c][t] fp32 -> Wt[t][o][c] bf16 ------------------
__global__ __launch_bounds__(256) void k_wprep(
    const float* __restrict__ Wb, __hip_bfloat16* __restrict__ Wt)
{
    int o = blockIdx.x;
    for (int c = threadIdx.x; c < CCH; c += 256) {
        const float* src = Wb + ((size_t)o*CCH + c)*9;
        #pragma unroll
        for (int t = 0; t < 9; ++t)
            Wt[((size_t)t*CCH + o)*CCH + c] = __float2bfloat16(src[t]);
    }
}

// ---------------- PI: build bconv input, transposed bf16 --------------------
// inb[b][p][c] = bf16( (1+xw[b,p]) * (f1[b,c,p] + alpha*f2[b,c,p] + gamma) )
__global__ __launch_bounds__(256) void k_prep_in(
    const float* __restrict__ f1, const float* __restrict__ f2,
    const float* __restrict__ alpha, const float* __restrict__ gamma,
    const float* __restrict__ xw,
    __hip_bfloat16* __restrict__ inb)
{
    int b = blockIdx.x;
    int tid = threadIdx.x;
    __shared__ float scm[81], sal[81], sga[81];
    __shared__ float ls[64][82];
    if (tid < 81) {
        scm[tid] = 1.f + xw[b*81+tid];
        sal[tid] = alpha[b*81+tid];
        sga[tid] = gamma[b*81+tid];
    }
    __syncthreads();
    for (int c0 = 0; c0 < CCH; c0 += 64) {
        __syncthreads();
        for (int i = tid; i < 64*81; i += 256) {
            int c = i / 81, p = i - c*81;
            size_t gidx = ((size_t)b*CCH + c0 + c)*PP + p;
            ls[c][p] = scm[p]*(f1[gidx] + sal[p]*f2[gidx] + sga[p]);
        }
        __syncthreads();
        for (int i = tid; i < 81*64; i += 256) {
            int p = i >> 6, c = i & 63;
            inb[((size_t)b*PP + p)*CCH + c0 + c] = __float2bfloat16(ls[c][p]);
        }
    }
}

// ---------------- KB v2: 3x3 bconv as bf16 MFMA GEMM ------------------------
// out[b,o,p] = BN+leaky( sum_t sum_c Wt[t][o][c] * inb[b][shift_t(p)][c] )
__global__ __launch_bounds__(256) void k_bconv_mfma(
    const __hip_bfloat16* __restrict__ inb,   // [B][81][768]
    const __hip_bfloat16* __restrict__ Wt,    // [9][768][768]
    const float* __restrict__ bn_g, const float* __restrict__ bn_b,
    const float* __restrict__ bn_m, const float* __restrict__ bn_v,
    float* __restrict__ out)
{
    int b  = blockIdx.x;
    int o0 = blockIdx.y * 128;
    int tid = threadIdx.x;
    int w    = tid >> 6;        // wave 0..3 -> M offset w*32
    int lane = tid & 63;
    int l15  = lane & 15;
    int kg   = lane >> 4;       // k-group 0..3

    __shared__ __align__(16) __hip_bfloat16 ls[82*40];  // [p 0..80 + zero row 81][40]

    // zero row 81 (stays zero; staging only writes rows 0..80)
    if (tid < 20) *(uint32_t*)&ls[81*40 + 2*tid] = 0u;

    // 54 static shift offsets (element offsets into ls), fully unrolled -> regs
    int spoff[9][6];
    #pragma unroll
    for (int t = 0; t < 9; ++t) {
        int dy = t/3 - 1, dx = t%3 - 1;
        #pragma unroll
        for (int n = 0; n < 6; ++n) {
            int p = n*16 + l15;
            int yy = p/9, xx = p - yy*9;
            int Y = yy + dy, X = xx + dx;
            bool ok = (p < PP) && (Y >= 0) && (Y < 9) && (X >= 0) && (X < 9);
            int sp = ok ? (Y*9 + X) : 81;
            spoff[t][n] = sp*40 + kg*8;
        }
    }

    f32x4 acc[2][6];
    #pragma unroll
    for (int mi = 0; mi < 2; ++mi)
        #pragma unroll
        for (int n = 0; n < 6; ++n)
            acc[mi][n] = (f32x4){0.f,0.f,0.f,0.f};

    const __hip_bfloat16* inbb = inb + (size_t)b*PP*CCH;

    for (int c0 = 0; c0 < CCH; c0 += 32) {
        __syncthreads();
        // stage rows 0..80, 32 channels, 4B per thread-op
        for (int i = tid; i < 81*16; i += 256) {
            int p = i >> 4, cp = i & 15;
            *(uint32_t*)&ls[p*40 + cp*2] =
                *(const uint32_t*)&inbb[(size_t)p*CCH + c0 + cp*2];
        }
        __syncthreads();
        #pragma unroll
        for (int t = 0; t < 9; ++t) {
            const __hip_bfloat16* wrow0 =
                Wt + (((size_t)t*CCH + o0 + w*32 + l15)*CCH + c0 + kg*8);
            short8v a0 = *(const short8v*)wrow0;
            short8v a1 = *(const short8v*)(wrow0 + 16*CCH);
            #pragma unroll
            for (int n = 0; n < 6; ++n) {
                short8v bf = *(const short8v*)&ls[spoff[t][n]];
                acc[0][n] = __builtin_amdgcn_mfma_f32_16x16x32_bf16(a0, bf, acc[0][n], 0, 0, 0);
                acc[1][n] = __builtin_amdgcn_mfma_f32_16x16x32_bf16(a1, bf, acc[1][n], 0, 0, 0);
            }
        }
    }

    // epilogue: D row=(lane>>4)*4+r, col=lane&15 (m89/m91-verified mapping)
    #pragma unroll
    for (int mi = 0; mi < 2; ++mi) {
        #pragma unroll
        for (int r = 0; r < 4; ++r) {
            int o = o0 + w*32 + mi*16 + kg*4 + r;
            float sc = bn_g[o] * rsqrtf(bn_v[o] + 1e-5f);
            float mn = bn_m[o], bt = bn_b[o];
            #pragma unroll
            for (int n = 0; n < 6; ++n) {
                int p = n*16 + l15;
                if (p < PP) {
                    float v = (acc[mi][n][r] - mn) * sc + bt;
                    out[((size_t)b*CCH + o)*PP + p] = (v > 0.f) ? v : 0.01f*v;
                }
            }
        }
    }
}

extern "C" void kernel_launch(void* const* d_in, const int* in_sizes, int n_in,
                              void* d_out, int out_size, void* d_ws, size_t ws_size,
                              hipStream_t stream)
{
    (void)in_sizes; (void)n_in; (void)out_size; (void)ws_size;
    const float* x    = (const float*)d_in[0];
    const float* y    = (const float*)d_in[1];
    const float* Wh1  = (const float*)d_in[2];
    const float* bh1  = (const float*)d_in[3];
    const float* W11  = (const float*)d_in[4];
    const float* b11  = (const float*)d_in[5];
    const float* Wh2  = (const float*)d_in[6];
    const float* bh2  = (const float*)d_in[7];
    const float* Wl1  = (const float*)d_in[8];
    const float* bl1  = (const float*)d_in[9];
    const float* wh3  = (const float*)d_in[10];
    const float* bh3  = (const float*)d_in[11];
    const float* wl2  = (const float*)d_in[12];
    const float* bl2  = (const float*)d_in[13];
    const float* W12  = (const float*)d_in[14];
    const float* b12  = (const float*)d_in[15];
    const float* Wl3  = (const float*)d_in[16];
    const float* bl3  = (const float*)d_in[17];
    const float* wcc  = (const float*)d_in[18];
    const float* bcc  = (const float*)d_in[19];
    const float* wpool= (const float*)d_in[20];
    const float* bpool= (const float*)d_in[21];
    const float* Wfc1 = (const float*)d_in[22];
    const float* bfc1 = (const float*)d_in[23];
    const float* Wfc2 = (const float*)d_in[24];
    const float* bfc2 = (const float*)d_in[25];
    const float* Wb   = (const float*)d_in[26];
    const float* bng  = (const float*)d_in[27];
    const float* bnb  = (const float*)d_in[28];
    const float* bnm  = (const float*)d_in[29];
    const float* bnv  = (const float*)d_in[30];
    float* out = (float*)d_out;
    float* ws = (float*)d_ws;

    size_t off = 0;
    float* f1    = ws + off; off += (size_t)BATCH*CCH*PP;
    float* f2    = ws + off; off += (size_t)BATCH*CCH*PP;
    float* WA    = ws + off; off += (size_t)CCH*CCH;
    float* WB    = ws + off; off += (size_t)CCH*LCH;
    float* beff  = ws + off; off += CCH;
    float* f3    = ws + off; off += BATCH*2*PP;
    float* f4    = ws + off; off += BATCH*2*PP;
    float* Af    = ws + off; off += BATCH*10*PP;
    float* Uf    = ws + off; off += BATCH*10*PP;
    float* f22   = ws + off; off += BATCH*PP;
    float* ccs   = ws + off; off += BATCH*PP;
    float* alpha = ws + off; off += BATCH*PP;
    float* gamma = ws + off; off += BATCH*PP;
    float* xw    = ws + off; off += BATCH*PP;
    __hip_bfloat16* inb = (__hip_bfloat16*)(ws + off); off += (size_t)BATCH*PP*CCH/2;
    __hip_bfloat16* Wt  = (__hip_bfloat16*)(ws + off); off += (size_t)9*CCH*CCH/2;
    // total ~175 MB of d_ws

    kw_compose<<<dim3(CCH), dim3(256), 0, stream>>>(W11, Wh2, Wl1, bh2, bl1, b11, WA, WB, beff);
    k_wprep<<<dim3(CCH), dim3(256), 0, stream>>>(Wb, Wt);
    k_fuse12<<<dim3(BATCH,12), dim3(256), 0, stream>>>(x, y, Wh1, bh1, WA, WB, beff, f1, f2);
    k_fuse34<<<dim3(81), dim3(256), 0, stream>>>(x, y, wh3, bh3, wl2, bl2, W12, b12, Wl3, bl3, f3, f4);
    k_ssim_wh<<<dim3(BATCH), dim3(128), 0, stream>>>(f3, f4, Af);
    k_ssim_b<<<dim3(810), dim3(256), 0, stream>>>(Af, Uf);
    k_ssim_comb<<<dim3(81), dim3(256), 0, stream>>>(Uf, f3, f4, wcc, bcc, f22, ccs);
    k_fc<<<dim3(BATCH), dim3(128), 0, stream>>>(f22, wpool, bpool, Wfc1, bfc1, Wfc2, bfc2, xw);
    k_cor2<<<dim3(BATCH), dim3(256), 0, stream>>>(f1, f2, f22, ccs, alpha, gamma);
    k_prep_in<<<dim3(BATCH), dim3(256), 0, stream>>>(f1, f2, alpha, gamma, xw, inb);
    k_bconv_mfma<<<dim3(BATCH,6), dim3(256), 0, stream>>>(inb, Wt, bng, bnb, bnm, bnv, out);
}

// Round 3
// 980.135 us; speedup vs baseline: 7.6176x; 1.9440x over previous
//
#include <hip/hip_runtime.h>
#include <hip/hip_bf16.h>
#include <math.h>

#define BATCH 256
#define CCH 768
#define LCH 64
#define PP 81

typedef __attribute__((ext_vector_type(8))) short short8v;
typedef __attribute__((ext_vector_type(4))) float f32x4;

// ---------------- KW: weight composition (emits bf16 directly) --------------
__global__ __launch_bounds__(256) void kw_compose(
    const float* __restrict__ W11, const float* __restrict__ Wh2,
    const float* __restrict__ Wl1, const float* __restrict__ bh2,
    const float* __restrict__ bl1, const float* __restrict__ b11,
    const float* __restrict__ Wh1,
    __hip_bfloat16* __restrict__ WAb, __hip_bfloat16* __restrict__ WBb,
    __hip_bfloat16* __restrict__ Wh1b, float* __restrict__ beff)
{
    int o = blockIdx.x;
    int t = threadIdx.x;
    const float* w11row = W11 + (size_t)o * CCH;
    for (int c = t; c < CCH; c += 256) {
        float s = 0.f;
        for (int k = 0; k < 512; ++k) s = fmaf(w11row[k], Wh2[(size_t)k*CCH + c], s);
        WAb[(size_t)o*CCH + c]  = __float2bfloat16(s);
        Wh1b[(size_t)o*CCH + c] = __float2bfloat16(Wh1[(size_t)o*CCH + c]);
    }
    if (t < LCH) {
        float s = 0.f;
        for (int k = 0; k < 256; ++k) s = fmaf(w11row[512+k], Wl1[k*LCH + t], s);
        WBb[o*LCH + t] = __float2bfloat16(s);
    }
    if (t == 0) {
        float s = b11[o];
        for (int k = 0; k < 512; ++k) s = fmaf(w11row[k], bh2[k], s);
        for (int k = 0; k < 256; ++k) s = fmaf(w11row[512+k], bl1[k], s);
        beff[o] = s;
    }
}

// ---------------- XP: transpose x,y to bf16 [b][p][c] -----------------------
__global__ __launch_bounds__(256) void k_xprep(
    const float* __restrict__ x, const float* __restrict__ y,
    __hip_bfloat16* __restrict__ xT, __hip_bfloat16* __restrict__ yT)
{
    int b = blockIdx.x;
    int tid = threadIdx.x;
    __shared__ float ls[64][82];
    for (int c0 = 0; c0 < CCH; c0 += 64) {
        __syncthreads();
        for (int i = tid; i < 64*81; i += 256) {
            int c = i / 81, p = i - c*81;
            ls[c][p] = x[((size_t)b*CCH + c0 + c)*PP + p];
        }
        __syncthreads();
        for (int i = tid; i < 81*64; i += 256) {
            int p = i >> 6, c = i & 63;
            xT[((size_t)b*PP + p)*CCH + c0 + c] = __float2bfloat16(ls[c][p]);
        }
    }
    __syncthreads();
    for (int i = tid; i < 64*81; i += 256) {
        int c = i / 81, p = i - c*81;
        ls[c][p] = y[((size_t)b*LCH + c)*PP + p];
    }
    __syncthreads();
    for (int i = tid; i < 81*64; i += 256) {
        int p = i >> 6, c = i & 63;
        yT[((size_t)b*PP + p)*LCH + c] = __float2bfloat16(ls[c][p]);
    }
}

// ---------------- K1 v2: fuse_1 / fuse_2 as bf16 MFMA GEMM ------------------
// f1[b,o,p] = Wh1·x  + bh1 ; f2[b,o,p] = WA·x + WB·y + beff  (fp32 out)
__global__ __launch_bounds__(256) void k_fuse12_mfma(
    const __hip_bfloat16* __restrict__ xT,    // [B][81][768]
    const __hip_bfloat16* __restrict__ yT,    // [B][81][64]
    const __hip_bfloat16* __restrict__ Wh1b,  // [768][768]
    const __hip_bfloat16* __restrict__ WAb,   // [768][768]
    const __hip_bfloat16* __restrict__ WBb,   // [768][64]
    const float* __restrict__ bh1, const float* __restrict__ beff,
    float* __restrict__ f1, float* __restrict__ f2)
{
    int b  = blockIdx.x;
    int o0 = blockIdx.y * 128;
    int tid = threadIdx.x;
    int w    = tid >> 6;
    int lane = tid & 63;
    int l15  = lane & 15;
    int kg   = lane >> 4;

    __shared__ __align__(16) __hip_bfloat16 ls[82*40];
    if (tid < 20) *(uint32_t*)&ls[81*40 + 2*tid] = 0u;

    int spoff[6];
    #pragma unroll
    for (int n = 0; n < 6; ++n) {
        int p = n*16 + l15;
        int sp = (p < PP) ? p : 81;
        spoff[n] = sp*40 + kg*8;
    }

    f32x4 acc[2][2][6];   // [out f1/f2][mi][n]
    #pragma unroll
    for (int u = 0; u < 2; ++u)
        #pragma unroll
        for (int mi = 0; mi < 2; ++mi)
            #pragma unroll
            for (int n = 0; n < 6; ++n)
                acc[u][mi][n] = (f32x4){0.f,0.f,0.f,0.f};

    const __hip_bfloat16* xb = xT + (size_t)b*PP*CCH;

    for (int c0 = 0; c0 < CCH; c0 += 32) {
        __syncthreads();
        for (int i = tid; i < 81*16; i += 256) {
            int p = i >> 4, cp = i & 15;
            *(uint32_t*)&ls[p*40 + cp*2] =
                *(const uint32_t*)&xb[(size_t)p*CCH + c0 + cp*2];
        }
        __syncthreads();
        const __hip_bfloat16* w1row = Wh1b + ((size_t)(o0 + w*32 + l15))*CCH + c0 + kg*8;
        const __hip_bfloat16* wArow = WAb  + ((size_t)(o0 + w*32 + l15))*CCH + c0 + kg*8;
        short8v a10 = *(const short8v*)w1row;
        short8v a11 = *(const short8v*)(w1row + 16*CCH);
        short8v a20 = *(const short8v*)wArow;
        short8v a21 = *(const short8v*)(wArow + 16*CCH);
        #pragma unroll
        for (int n = 0; n < 6; ++n) {
            short8v bf = *(const short8v*)&ls[spoff[n]];
            acc[0][0][n] = __builtin_amdgcn_mfma_f32_16x16x32_bf16(a10, bf, acc[0][0][n], 0, 0, 0);
            acc[0][1][n] = __builtin_amdgcn_mfma_f32_16x16x32_bf16(a11, bf, acc[0][1][n], 0, 0, 0);
            acc[1][0][n] = __builtin_amdgcn_mfma_f32_16x16x32_bf16(a20, bf, acc[1][0][n], 0, 0, 0);
            acc[1][1][n] = __builtin_amdgcn_mfma_f32_16x16x32_bf16(a21, bf, acc[1][1][n], 0, 0, 0);
        }
    }

    // y extension: K=64, f2 only
    const __hip_bfloat16* yb = yT + (size_t)b*PP*LCH;
    for (int l0 = 0; l0 < LCH; l0 += 32) {
        __syncthreads();
        for (int i = tid; i < 81*16; i += 256) {
            int p = i >> 4, cp = i & 15;
            *(uint32_t*)&ls[p*40 + cp*2] =
                *(const uint32_t*)&yb[(size_t)p*LCH + l0 + cp*2];
        }
        __syncthreads();
        const __hip_bfloat16* wBrow = WBb + ((size_t)(o0 + w*32 + l15))*LCH + l0 + kg*8;
        short8v a0 = *(const short8v*)wBrow;
        short8v a1 = *(const short8v*)(wBrow + 16*LCH);
        #pragma unroll
        for (int n = 0; n < 6; ++n) {
            short8v bf = *(const short8v*)&ls[spoff[n]];
            acc[1][0][n] = __builtin_amdgcn_mfma_f32_16x16x32_bf16(a0, bf, acc[1][0][n], 0, 0, 0);
            acc[1][1][n] = __builtin_amdgcn_mfma_f32_16x16x32_bf16(a1, bf, acc[1][1][n], 0, 0, 0);
        }
    }

    #pragma unroll
    for (int mi = 0; mi < 2; ++mi) {
        #pragma unroll
        for (int r = 0; r < 4; ++r) {
            int o = o0 + w*32 + mi*16 + kg*4 + r;
            float b1 = bh1[o], b2 = beff[o];
            #pragma unroll
            for (int n = 0; n < 6; ++n) {
                int p = n*16 + l15;
                if (p < PP) {
                    size_t idx = ((size_t)b*CCH + o)*PP + p;
                    f1[idx] = acc[0][mi][n][r] + b1;
                    f2[idx] = acc[1][mi][n][r] + b2;
                }
            }
        }
    }
}

// ---------------- S1: fuse_3 / fuse_4 ------
__global__ __launch_bounds__(256) void k_fuse34(
    const float* __restrict__ x, const float* __restrict__ y,
    const float* __restrict__ wh3, const float* __restrict__ bh3,
    const float* __restrict__ wl2, const float* __restrict__ bl2,
    const float* __restrict__ W12, const float* __restrict__ b12,
    const float* __restrict__ Wl3, const float* __restrict__ bl3,
    float* __restrict__ f3, float* __restrict__ f4)
{
    int t = blockIdx.x * 256 + threadIdx.x;
    if (t >= BATCH*PP) return;
    int b = t / PP, p = t - b*PP;
    const float* xb = x + (size_t)b*CCH*PP + p;
    const float* yb = y + (size_t)b*LCH*PP + p;
    float sx = 0.f;
    for (int c = 0; c < CCH; ++c) sx = fmaf(wh3[c], xb[(size_t)c*PP], sx);
    float sy = 0.f, s40 = 0.f, s41 = 0.f;
    for (int l = 0; l < LCH; ++l) {
        float v = yb[(size_t)l*PP];
        sy  = fmaf(wl2[l], v, sy);
        s40 = fmaf(Wl3[l], v, s40);
        s41 = fmaf(Wl3[LCH+l], v, s41);
    }
    float t3a = sx + bh3[0];
    float t3b = sy + bl2[0];
    f3[(b*2+0)*PP+p] = W12[0]*t3a + W12[1]*t3b + b12[0];
    f3[(b*2+1)*PP+p] = W12[2]*t3a + W12[3]*t3b + b12[1];
    f4[(b*2+0)*PP+p] = s40 + bl3[0];
    f4[(b*2+1)*PP+p] = s41 + bl3[1];
}

// ---------------- S2: SSIM box-7 along w,h ------------
__global__ __launch_bounds__(128) void k_ssim_wh(
    const float* __restrict__ f3, const float* __restrict__ f4,
    float* __restrict__ A)
{
    int b = blockIdx.x;
    int tid = threadIdx.x;
    __shared__ float z[10][81];
    __shared__ float tb[10][81];
    for (int i = tid; i < 2*81; i += 128) {
        int k = i / 81, p = i - k*81;
        float a = f3[(b*2+k)*81+p];
        float c = f4[(b*2+k)*81+p];
        z[k*5+0][p] = a;   z[k*5+1][p] = c;
        z[k*5+2][p] = a*a; z[k*5+3][p] = c*c; z[k*5+4][p] = a*c;
    }
    __syncthreads();
    for (int i = tid; i < 10*81; i += 128) {
        int f = i / 81, p = i - f*81;
        int yy = p/9, xx = p - yy*9;
        float s = 0.f;
        #pragma unroll
        for (int d = -3; d <= 3; ++d) {
            int j = xx + d;
            j = (j < 0) ? (-1-j) : ((j > 8) ? (17-j) : j);
            s += z[f][yy*9+j];
        }
        tb[f][p] = s * (1.f/7.f);
    }
    __syncthreads();
    for (int i = tid; i < 10*81; i += 128) {
        int f = i / 81, p = i - f*81;
        int yy = p/9, xx = p - yy*9;
        float s = 0.f;
        #pragma unroll
        for (int d = -3; d <= 3; ++d) {
            int j = yy + d;
            j = (j < 0) ? (-1-j) : ((j > 8) ? (17-j) : j);
            s += tb[f][j*9+xx];
        }
        A[((size_t)b*10 + f)*81 + p] = s * (1.f/7.f);
    }
}

// ---------------- S3: box-7 along batch ----------
__global__ __launch_bounds__(256) void k_ssim_b(
    const float* __restrict__ A, float* __restrict__ U)
{
    int col = blockIdx.x;
    int b = threadIdx.x;
    float s = 0.f;
    #pragma unroll
    for (int d = -3; d <= 3; ++d) {
        int j = b + d;
        j = (j < 0) ? (-1-j) : ((j > 255) ? (511-j) : j);
        s += A[(size_t)j*810 + col];
    }
    U[(size_t)b*810 + col] = s * (1.f/7.f);
}

// ---------------- S4: SSIM map + fuse2_2 + cc(ssim) -------------------------
__global__ __launch_bounds__(256) void k_ssim_comb(
    const float* __restrict__ U, const float* __restrict__ f3,
    const float* __restrict__ f4, const float* __restrict__ wcc,
    const float* __restrict__ bcc,
    float* __restrict__ f22, float* __restrict__ ccs)
{
    int t = blockIdx.x * 256 + threadIdx.x;
    if (t >= BATCH*81) return;
    int b = t / 81, p = t - b*81;
    const float cov = 343.f/342.f, C1c = 1e-4f, C2c = 9e-4f;
    float S[2];
    #pragma unroll
    for (int k = 0; k < 2; ++k) {
        const float* u = U + (size_t)b*810 + (k*5)*81 + p;
        float ux = u[0], uy = u[81], uxx = u[162], uyy = u[243], uxy = u[324];
        float vx = cov*(uxx - ux*ux), vy = cov*(uyy - uy*uy), vxy = cov*(uxy - ux*uy);
        S[k] = ((2.f*ux*uy + C1c)*(2.f*vxy + C2c)) /
               ((ux*ux + uy*uy + C1c)*(vx + vy + C2c));
    }
    float a0 = f4[(b*2+0)*81+p] + S[0]*f3[(b*2+0)*81+p];
    float a1 = f4[(b*2+1)*81+p] + S[1]*f3[(b*2+1)*81+p];
    f22[t] = wcc[0]*a0 + wcc[1]*a1 + bcc[0];
    ccs[t] = wcc[0]*S[0] + wcc[1]*S[1] + bcc[0];
}

// ---------------- C1 v2: coalesced channel sums -> alpha, gamma -------------
__global__ __launch_bounds__(256) void k_cor2(
    const float* __restrict__ f1, const float* __restrict__ f2,
    const float* __restrict__ f22, const float* __restrict__ ccs,
    float* __restrict__ alpha, float* __restrict__ gamma)
{
    int b = blockIdx.x;
    int tid = threadIdx.x;
    bool act = tid < 243;
    float Sxx=0.f, Syy=0.f, Sxy=0.f, Sx=0.f, Sy=0.f;
    const float* A = f1 + (size_t)b*CCH*PP;
    const float* C = f2 + (size_t)b*CCH*PP;
    if (act) {
        for (int c0 = 0; c0 < CCH; c0 += 3) {
            float u = A[(size_t)c0*PP + tid];
            float v = C[(size_t)c0*PP + tid];
            Sxx = fmaf(u,u,Sxx); Syy = fmaf(v,v,Syy); Sxy = fmaf(u,v,Sxy);
            Sx += u; Sy += v;
        }
    }
    __shared__ float red[243][5];
    if (act) {
        red[tid][0]=Sxx; red[tid][1]=Syy; red[tid][2]=Sxy; red[tid][3]=Sx; red[tid][4]=Sy;
    }
    __syncthreads();
    if (tid < 81) {
        float xx = red[tid][0]+red[tid+81][0]+red[tid+162][0];
        float yy = red[tid][1]+red[tid+81][1]+red[tid+162][1];
        float xy = red[tid][2]+red[tid+81][2]+red[tid+162][2];
        float sx = red[tid][3]+red[tid+81][3]+red[tid+162][3];
        float sy = red[tid][4]+red[tid+81][4]+red[tid+162][4];
        float cor1 = xy / fmaxf(sqrtf(xx)*sqrtf(yy), 1e-8f);
        float al = 0.5f*(1.f - cor1);
        float sum21 = sx + al*sy;
        float n21 = sqrtf(fmaxf(xx + 2.f*al*xy + al*al*yy, 0.f));
        int t = b*81 + tid;
        float fv = f22[t];
        float cor2 = (fv * sum21) / fmaxf(n21 * 27.712812921102035f * fabsf(fv), 1e-8f);
        float be = 0.5f*(1.f - cor2 + ccs[t]);
        alpha[t] = al;
        gamma[t] = be * fv;
    }
}

// ---------------- F: pool conv + fc1(gelu) + fc2(leaky) -> xweight -----
__global__ __launch_bounds__(128) void k_fc(
    const float* __restrict__ f22,
    const float* __restrict__ wpool, const float* __restrict__ bpool,
    const float* __restrict__ Wfc1, const float* __restrict__ bfc1,
    const float* __restrict__ Wfc2, const float* __restrict__ bfc2,
    float* __restrict__ xw)
{
    int b = blockIdx.x;
    int tid = threadIdx.x;
    __shared__ float xc[324];
    __shared__ float h1[324];
    for (int p = tid; p < 81; p += 128) {
        float v = f22[b*81+p];
        xc[p] = v; xc[243+p] = v;
    }
    __syncthreads();
    for (int i = tid; i < 162; i += 128) {
        int k = i / 81, p = i - k*81;
        int yy = p/9, xx = p - yy*9;
        float s = bpool[k];
        #pragma unroll
        for (int dy = -1; dy <= 1; ++dy)
            #pragma unroll
            for (int dx = -1; dx <= 1; ++dx) {
                int Y = yy+dy, X = xx+dx;
                if (Y >= 0 && Y < 9 && X >= 0 && X < 9)
                    s = fmaf(wpool[k*9 + (dy+1)*3 + (dx+1)], xc[Y*9+X], s);
            }
        xc[81+i] = s;
    }
    __syncthreads();
    for (int i = tid; i < 324; i += 128) {
        float s = bfc1[i];
        const float* wr = Wfc1 + (size_t)i*324;
        for (int j = 0; j < 324; ++j) s = fmaf(wr[j], xc[j], s);
        h1[i] = 0.5f*s*(1.f + erff(s*0.70710678118654752f));
    }
    __syncthreads();
    for (int q = tid; q < 81; q += 128) {
        float s = bfc2[q];
        const float* wr = Wfc2 + (size_t)q*324;
        for (int j = 0; j < 324; ++j) s = fmaf(wr[j], h1[j], s);
        xw[b*81+q] = (s > 0.f) ? s : 0.01f*s;
    }
}

// ---------------- WP: Wb[o][c][t] fp32 -> Wt[t][o][c] bf16 ------------------
__global__ __launch_bounds__(256) void k_wprep(
    const float* __restrict__ Wb, __hip_bfloat16* __restrict__ Wt)
{
    int o = blockIdx.x;
    for (int c = threadIdx.x; c < CCH; c += 256) {
        const float* src = Wb + ((size_t)o*CCH + c)*9;
        #pragma unroll
        for (int t = 0; t < 9; ++t)
            Wt[((size_t)t*CCH + o)*CCH + c] = __float2bfloat16(src[t]);
    }
}

// ---------------- PI: build bconv input, transposed bf16 --------------------
__global__ __launch_bounds__(256) void k_prep_in(
    const float* __restrict__ f1, const float* __restrict__ f2,
    const float* __restrict__ alpha, const float* __restrict__ gamma,
    const float* __restrict__ xw,
    __hip_bfloat16* __restrict__ inb)
{
    int b = blockIdx.x;
    int tid = threadIdx.x;
    __shared__ float scm[81], sal[81], sga[81];
    __shared__ float ls[64][82];
    if (tid < 81) {
        scm[tid] = 1.f + xw[b*81+tid];
        sal[tid] = alpha[b*81+tid];
        sga[tid] = gamma[b*81+tid];
    }
    __syncthreads();
    for (int c0 = 0; c0 < CCH; c0 += 64) {
        __syncthreads();
        for (int i = tid; i < 64*81; i += 256) {
            int c = i / 81, p = i - c*81;
            size_t gidx = ((size_t)b*CCH + c0 + c)*PP + p;
            ls[c][p] = scm[p]*(f1[gidx] + sal[p]*f2[gidx] + sga[p]);
        }
        __syncthreads();
        for (int i = tid; i < 81*64; i += 256) {
            int p = i >> 6, c = i & 63;
            inb[((size_t)b*PP + p)*CCH + c0 + c] = __float2bfloat16(ls[c][p]);
        }
    }
}

// ---------------- KB v2: 3x3 bconv as bf16 MFMA GEMM ------------------------
__global__ __launch_bounds__(256) void k_bconv_mfma(
    const __hip_bfloat16* __restrict__ inb,   // [B][81][768]
    const __hip_bfloat16* __restrict__ Wt,    // [9][768][768]
    const float* __restrict__ bn_g, const float* __restrict__ bn_b,
    const float* __restrict__ bn_m, const float* __restrict__ bn_v,
    float* __restrict__ out)
{
    int b  = blockIdx.x;
    int o0 = blockIdx.y * 128;
    int tid = threadIdx.x;
    int w    = tid >> 6;
    int lane = tid & 63;
    int l15  = lane & 15;
    int kg   = lane >> 4;

    __shared__ __align__(16) __hip_bfloat16 ls[82*40];

    if (tid < 20) *(uint32_t*)&ls[81*40 + 2*tid] = 0u;

    int spoff[9][6];
    #pragma unroll
    for (int t = 0; t < 9; ++t) {
        int dy = t/3 - 1, dx = t%3 - 1;
        #pragma unroll
        for (int n = 0; n < 6; ++n) {
            int p = n*16 + l15;
            int yy = p/9, xx = p - yy*9;
            int Y = yy + dy, X = xx + dx;
            bool ok = (p < PP) && (Y >= 0) && (Y < 9) && (X >= 0) && (X < 9);
            int sp = ok ? (Y*9 + X) : 81;
            spoff[t][n] = sp*40 + kg*8;
        }
    }

    f32x4 acc[2][6];
    #pragma unroll
    for (int mi = 0; mi < 2; ++mi)
        #pragma unroll
        for (int n = 0; n < 6; ++n)
            acc[mi][n] = (f32x4){0.f,0.f,0.f,0.f};

    const __hip_bfloat16* inbb = inb + (size_t)b*PP*CCH;

    for (int c0 = 0; c0 < CCH; c0 += 32) {
        __syncthreads();
        for (int i = tid; i < 81*16; i += 256) {
            int p = i >> 4, cp = i & 15;
            *(uint32_t*)&ls[p*40 + cp*2] =
                *(const uint32_t*)&inbb[(size_t)p*CCH + c0 + cp*2];
        }
        __syncthreads();
        #pragma unroll
        for (int t = 0; t < 9; ++t) {
            const __hip_bfloat16* wrow0 =
                Wt + (((size_t)t*CCH + o0 + w*32 + l15)*CCH + c0 + kg*8);
            short8v a0 = *(const short8v*)wrow0;
            short8v a1 = *(const short8v*)(wrow0 + 16*CCH);
            #pragma unroll
            for (int n = 0; n < 6; ++n) {
                short8v bf = *(const short8v*)&ls[spoff[t][n]];
                acc[0][n] = __builtin_amdgcn_mfma_f32_16x16x32_bf16(a0, bf, acc[0][n], 0, 0, 0);
                acc[1][n] = __builtin_amdgcn_mfma_f32_16x16x32_bf16(a1, bf, acc[1][n], 0, 0, 0);
            }
        }
    }

    #pragma unroll
    for (int mi = 0; mi < 2; ++mi) {
        #pragma unroll
        for (int r = 0; r < 4; ++r) {
            int o = o0 + w*32 + mi*16 + kg*4 + r;
            float sc = bn_g[o] * rsqrtf(bn_v[o] + 1e-5f);
            float mn = bn_m[o], bt = bn_b[o];
            #pragma unroll
            for (int n = 0; n < 6; ++n) {
                int p = n*16 + l15;
                if (p < PP) {
                    float v = (acc[mi][n][r] - mn) * sc + bt;
                    out[((size_t)b*CCH + o)*PP + p] = (v > 0.f) ? v : 0.01f*v;
                }
            }
        }
    }
}

extern "C" void kernel_launch(void* const* d_in, const int* in_sizes, int n_in,
                              void* d_out, int out_size, void* d_ws, size_t ws_size,
                              hipStream_t stream)
{
    (void)in_sizes; (void)n_in; (void)out_size; (void)ws_size;
    const float* x    = (const float*)d_in[0];
    const float* y    = (const float*)d_in[1];
    const float* Wh1  = (const float*)d_in[2];
    const float* bh1  = (const float*)d_in[3];
    const float* W11  = (const float*)d_in[4];
    const float* b11  = (const float*)d_in[5];
    const float* Wh2  = (const float*)d_in[6];
    const float* bh2  = (const float*)d_in[7];
    const float* Wl1  = (const float*)d_in[8];
    const float* bl1  = (const float*)d_in[9];
    const float* wh3  = (const float*)d_in[10];
    const float* bh3  = (const float*)d_in[11];
    const float* wl2  = (const float*)d_in[12];
    const float* bl2  = (const float*)d_in[13];
    const float* W12  = (const float*)d_in[14];
    const float* b12  = (const float*)d_in[15];
    const float* Wl3  = (const float*)d_in[16];
    const float* bl3  = (const float*)d_in[17];
    const float* wcc  = (const float*)d_in[18];
    const float* bcc  = (const float*)d_in[19];
    const float* wpool= (const float*)d_in[20];
    const float* bpool= (const float*)d_in[21];
    const float* Wfc1 = (const float*)d_in[22];
    const float* bfc1 = (const float*)d_in[23];
    const float* Wfc2 = (const float*)d_in[24];
    const float* bfc2 = (const float*)d_in[25];
    const float* Wb   = (const float*)d_in[26];
    const float* bng  = (const float*)d_in[27];
    const float* bnb  = (const float*)d_in[28];
    const float* bnm  = (const float*)d_in[29];
    const float* bnv  = (const float*)d_in[30];
    float* out = (float*)d_out;
    float* ws = (float*)d_ws;

    size_t off = 0;
    float* f1    = ws + off; off += (size_t)BATCH*CCH*PP;
    float* f2    = ws + off; off += (size_t)BATCH*CCH*PP;
    float* beff  = ws + off; off += CCH;
    float* f3    = ws + off; off += BATCH*2*PP;
    float* f4    = ws + off; off += BATCH*2*PP;
    float* Af    = ws + off; off += BATCH*10*PP;
    float* Uf    = ws + off; off += BATCH*10*PP;
    float* f22   = ws + off; off += BATCH*PP;
    float* ccs   = ws + off; off += BATCH*PP;
    float* alpha = ws + off; off += BATCH*PP;
    float* gamma = ws + off; off += BATCH*PP;
    float* xw    = ws + off; off += BATCH*PP;
    off = (off + 3) & ~(size_t)3;   // 16B-align the bf16 region
    __hip_bfloat16* Wh1b = (__hip_bfloat16*)(ws + off); off += (size_t)CCH*CCH/2;
    __hip_bfloat16* WAb  = (__hip_bfloat16*)(ws + off); off += (size_t)CCH*CCH/2;
    __hip_bfloat16* WBb  = (__hip_bfloat16*)(ws + off); off += (size_t)CCH*LCH/2;
    __hip_bfloat16* yT   = (__hip_bfloat16*)(ws + off); off += (size_t)BATCH*PP*LCH/2;
    __hip_bfloat16* inb  = (__hip_bfloat16*)(ws + off); off += (size_t)BATCH*PP*CCH/2;
    __hip_bfloat16* Wt   = (__hip_bfloat16*)(ws + off); off += (size_t)9*CCH*CCH/2;
    // xT aliases inb: k_fuse12_mfma consumes xT before k_prep_in overwrites it
    __hip_bfloat16* xT = inb;
    // total ~180 MB of d_ws

    kw_compose<<<dim3(CCH), dim3(256), 0, stream>>>(W11, Wh2, Wl1, bh2, bl1, b11, Wh1, WAb, WBb, Wh1b, beff);
    k_wprep<<<dim3(CCH), dim3(256), 0, stream>>>(Wb, Wt);
    k_xprep<<<dim3(BATCH), dim3(256), 0, stream>>>(x, y, xT, yT);
    k_fuse12_mfma<<<dim3(BATCH,6), dim3(256), 0, stream>>>(xT, yT, Wh1b, WAb, WBb, bh1, beff, f1, f2);
    k_fuse34<<<dim3(81), dim3(256), 0, stream>>>(x, y, wh3, bh3, wl2, bl2, W12, b12, Wl3, bl3, f3, f4);
    k_ssim_wh<<<dim3(BATCH), dim3(128), 0, stream>>>(f3, f4, Af);
    k_ssim_b<<<dim3(810), dim3(256), 0, stream>>>(Af, Uf);
    k_ssim_comb<<<dim3(81), dim3(256), 0, stream>>>(Uf, f3, f4, wcc, bcc, f22, ccs);
    k_fc<<<dim3(BATCH), dim3(128), 0, stream>>>(f22, wpool, bpool, Wfc1, bfc1, Wfc2, bfc2, xw);
    k_cor2<<<dim3(BATCH), dim3(256), 0, stream>>>(f1, f2, f22, ccs, alpha, gamma);
    k_prep_in<<<dim3(BATCH), dim3(256), 0, stream>>>(f1, f2, alpha, gamma, xw, inb);
    k_bconv_mfma<<<dim3(BATCH,6), dim3(256), 0, stream>>>(inb, Wt, bng, bnb, bnm, bnv, out);
}